// Round 13
// baseline (572.444 us; speedup 1.0000x reference)
//
#include <hip/hip_runtime.h>
#include <hip/hip_fp16.h>

// GATConv: N=50000, E=1600000, DIM_IN=256, HEADS=4, DIM_OUT=32 (HC=128)
// R23: front-end fused into ONE standard kernel via last-done flags (no coop):
//   grid = 391 bin + 391 proj + 196 csr = 978 blocks, ALL co-resident
//   (36.9KB LDS -> 4 blk/CU; launch_bounds(512,8) -> <=64 VGPR; cap = 1024)
//   so spin-waits cannot deadlock. bin[0..63] also transpose W -> flags[0];
//   bin done -> flags[1]; proj acquires flags[0]; csr acquires flags[1].
//   Pipeline: memset(gcur0+flags); D1 mega; D2 agg (R22 agg unchanged).

#define DIN 256
#define HC 128
#define NH 4
#define NEG 0.2f
#define BCAP 12288
#define LOG2E 1.44269504f

typedef _Float16 half8 __attribute__((ext_vector_type(8)));
typedef _Float16 half2v __attribute__((ext_vector_type(2)));
typedef float f32x4 __attribute__((ext_vector_type(4)));

// ---------------- projection body (MFMA) + fused attention logits ----------------
// Per-sub-block sm layout (18432B): xs [64][40] halves @0; Wl [128][40] @5120;
//   ep [64][136] @0 (reused); attSL @17408, attDL @17920.
// tid = sub-block-local thread id (0..255).
// a_src/a_dst written PRE-SCALED by log2(e) for agg's exp2f.
__device__ __forceinline__ void proj_body(char* sm, int tid, const float* __restrict__ x,
                                          const _Float16* __restrict__ Wt,
                                          const float* __restrict__ attS,
                                          const float* __restrict__ attD,
                                          __half* __restrict__ xph,
                                          float* __restrict__ a_src,
                                          float* __restrict__ a_dst, int n, int node0) {
    _Float16* xs = (_Float16*)sm;
    _Float16* Wl = (_Float16*)(sm + 5120);
    _Float16* ep = (_Float16*)sm;
    float* attSL = (float*)(sm + 17408);
    float* attDL = (float*)(sm + 17920);

    const int wave = tid >> 6;
    const int lane = tid & 63;
    const int l15  = lane & 15;
    const int quad = lane >> 4;

    if (tid < 128) attSL[tid] = attS[tid];
    else           attDL[tid - 128] = attD[tid - 128];

    f32x4 acc[8];
#pragma unroll
    for (int ct = 0; ct < 8; ++ct) acc[ct] = (f32x4){0.f, 0.f, 0.f, 0.f};

    for (int kt = 0; kt < DIN; kt += 32) {
        __syncthreads();
#pragma unroll
        for (int r = 0; r < 4; ++r) {
            int idx = tid + r * 256;
            int row = idx >> 4;
            int kp  = idx & 15;
            int gn = node0 + row;
            float2 xv = make_float2(0.f, 0.f);
            if (gn < n) xv = *(const float2*)&x[(size_t)gn * DIN + kt + kp * 2];
            half2v p; p[0] = (_Float16)xv.x; p[1] = (_Float16)xv.y;
            *(half2v*)&xs[row * 40 + kp * 2] = p;
        }
#pragma unroll
        for (int r = 0; r < 2; ++r) {
            int id = tid + r * 256;
            int c = id >> 2;
            int q = id & 3;
            half8 wv = *(const half8*)&Wt[(size_t)c * 256 + kt + q * 8];
            *(half8*)&Wl[c * 40 + q * 8] = wv;
        }
        __syncthreads();
        half8 af = *(const half8*)&xs[(wave * 16 + l15) * 40 + quad * 8];
#pragma unroll
        for (int ct = 0; ct < 8; ++ct) {
            half8 bf = *(const half8*)&Wl[(ct * 16 + l15) * 40 + quad * 8];
            acc[ct] = __builtin_amdgcn_mfma_f32_16x16x32_f16(af, bf, acc[ct], 0, 0, 0);
        }
    }
    __syncthreads();
#pragma unroll
    for (int ct = 0; ct < 8; ++ct)
#pragma unroll
        for (int r = 0; r < 4; ++r) {
            int row = wave * 16 + quad * 4 + r;
            ep[row * 136 + ct * 16 + l15] = (_Float16)acc[ct][r];
        }
    __syncthreads();
    {
        int row = tid >> 2, ch = tid & 3;
        int node = node0 + row;
        if (node < n) {
            const uint4* s = (const uint4*)&ep[row * 136 + ch * 32];
            uint4* d = (uint4*)&xph[(size_t)node * HC + ch * 32];
            d[0] = s[0]; d[1] = s[1]; d[2] = s[2]; d[3] = s[3];
        }
    }
    {
        int nl = tid >> 2, h = tid & 3;
        int node = node0 + nl;
        if (node < n) {
            float ps = 0.f, pd = 0.f;
            const _Float16* er = &ep[nl * 136 + h * 32];
#pragma unroll
            for (int c = 0; c < 32; ++c) {
                float v = (float)er[c];
                ps += v * attSL[h * 32 + c];
                pd += v * attDL[h * 32 + c];
            }
            a_src[node * NH + h] = ps * LOG2E;
            a_dst[node * NH + h] = pd * LOG2E;
        }
    }
}

// ---------------- bin role: one 4096-edge chunk, 512t, self-allocating buckets ----------------
__device__ __forceinline__ void bin_role(char* sm, const int* __restrict__ ei,
                                         int* __restrict__ gcur0,
                                         unsigned* __restrict__ binned,
                                         int e, int n, int chunk) {
    int* h     = (int*)sm;
    int* rbase = (int*)(sm + 1024);
    const int tid = threadIdx.x;
    if (tid < 256) h[tid] = 0;
    __syncthreads();
    const int base = chunk * 4096;
    unsigned pk[8];
    int bk[8];
#pragma unroll
    for (int j = 0; j < 8; ++j) {
        int i = base + j * 512 + tid;
        bk[j] = -1;
        if (i < e) {
            int src = ei[i];
            int dst = ei[e + i];
            if ((unsigned)dst < (unsigned)n && (unsigned)src < (unsigned)n) {
                bk[j] = dst >> 8;
                pk[j] = ((unsigned)(dst & 255) << 16) | (unsigned)src;
                atomicAdd(&h[bk[j]], 1);
            }
        }
    }
    __syncthreads();
    if (tid < 256) {
        if (h[tid]) rbase[tid] = atomicAdd(&gcur0[tid], h[tid]);
        h[tid] = 0;
    }
    __syncthreads();
#pragma unroll
    for (int j = 0; j < 8; ++j) {
        if (bk[j] >= 0) {
            int p = atomicAdd(&h[bk[j]], 1);
            int pib = rbase[bk[j]] + p;
            if (pib < BCAP) binned[(size_t)bk[j] * BCAP + pib] = pk[j];
        }
    }
}

// ---------------- csr role: one bucket counting sort, 512t two-pass ----------------
__device__ __forceinline__ void csr_role(char* sm, const unsigned* __restrict__ binned,
                                         const int* __restrict__ gcnt,
                                         int* __restrict__ off, int* __restrict__ deg,
                                         unsigned short* __restrict__ srt, int n, int b) {
    int* cnt = (int*)sm;
    int* buf = (int*)(sm + 1024);
    int* cur = (int*)(sm + 2048);
    const int tid = threadIdx.x;
    if (tid < 256) { buf[tid] = min(gcnt[tid], BCAP); cnt[tid] = 0; }
    __syncthreads();
    for (int s = 1; s < 256; s <<= 1) {
        int t = (tid < 256 && tid >= s) ? buf[tid - s] : 0;
        __syncthreads();
        if (tid < 256) buf[tid] += t;
        __syncthreads();
    }
    const int cb = min(gcnt[b], BCAP);
    const int excl = buf[b] - cb;                // exclusive scan of counts
    const int pgbase = ((excl + 31) & ~31) + b * 8192;
    const int kb = b * BCAP;
    const int ke = kb + cb;
    __syncthreads();                             // buf reads done before reuse
    for (int i = kb + tid; i < ke; i += 512)
        atomicAdd(&cnt[binned[i] >> 16], 1);
    __syncthreads();
    int v = 0;
    if (tid < 256) { v = cnt[tid]; buf[tid] = (v + 31) & ~31; }
    __syncthreads();
    for (int s = 1; s < 256; s <<= 1) {
        int t = (tid < 256 && tid >= s) ? buf[tid - s] : 0;
        __syncthreads();
        if (tid < 256) buf[tid] += t;
        __syncthreads();
    }
    if (tid < 256) {
        const int myoff = pgbase + buf[tid] - ((v + 31) & ~31);   // 32-aligned
        const int node = b * 256 + tid;
        if (node < n) { off[node] = myoff; deg[node] = v; }
        cur[tid] = myoff;
    }
    __syncthreads();
    for (int i = kb + tid; i < ke; i += 512) {
        unsigned pv = binned[i];
        int nl = pv >> 16;
        int pos = atomicAdd(&cur[nl], 1);
        srt[pos] = (unsigned short)(pv & 0xFFFFu);
    }
}

// ---------------- D1: fused front-end (bin+wtrans || proj || csr), flag-synced ----------------
// ALL blocks co-resident by construction (978 blocks; 4 blk/CU LDS-limit x 256 CU
// = 1024 slots; launch_bounds(512,8) forces <=64 VGPR so VGPRs also allow 4/CU)
// -> spin-wait cannot deadlock, no dispatch-order assumption.
__global__ __launch_bounds__(512, 8) void k_mega(const int* __restrict__ ei,
                                                 int* __restrict__ gcur0,
                                                 int* __restrict__ flags,
                                                 unsigned* __restrict__ binned,
                                                 const float* __restrict__ x,
                                                 const float* __restrict__ W,
                                                 _Float16* __restrict__ Wt,
                                                 const float* __restrict__ attS,
                                                 const float* __restrict__ attD,
                                                 __half* __restrict__ xph,
                                                 float* __restrict__ a_src,
                                                 float* __restrict__ a_dst,
                                                 int* __restrict__ off,
                                                 int* __restrict__ deg,
                                                 unsigned short* __restrict__ srt,
                                                 int e, int n, int ech, int pbh, int nbuck) {
    __shared__ __attribute__((aligned(16))) char sm[36864];
    const int bid = blockIdx.x;
    const int tid = threadIdx.x;

    if (bid < ech) {
        // ---- bin role; first 64 blocks transpose W first and release flags[0] ----
        if (bid < 64) {
            int idx = bid * 512 + tid;              // 64*512 = 32768 = DIN*HC
            int k = idx >> 7, c = idx & 127;
            Wt[c * 256 + k] = (_Float16)W[idx];
            __threadfence();
            __syncthreads();
            if (tid == 0)
                __hip_atomic_fetch_add(&flags[0], 1, __ATOMIC_RELEASE, __HIP_MEMORY_SCOPE_AGENT);
        }
        bin_role(sm, ei, gcur0, binned, e, n, bid);
        __threadfence();
        __syncthreads();
        if (tid == 0)
            __hip_atomic_fetch_add(&flags[1], 1, __ATOMIC_RELEASE, __HIP_MEMORY_SCOPE_AGENT);
    } else if (bid < ech + pbh) {
        // ---- proj role: wait for Wt (64 wtrans blocks) ----
        if (tid == 0) {
            while (__hip_atomic_load(&flags[0], __ATOMIC_ACQUIRE, __HIP_MEMORY_SCOPE_AGENT) < 64)
                __builtin_amdgcn_s_sleep(32);
        }
        __syncthreads();
        __threadfence();
        const int sub = tid >> 8;                   // 0 or 1
        const int t2  = tid & 255;
        const int tile = (bid - ech) * 2 + sub;
        proj_body(sm + sub * 18432, t2, x, Wt, attS, attD, xph, a_src, a_dst, n, tile * 64);
    } else {
        // ---- csr role: wait for all bin blocks ----
        if (tid == 0) {
            while (__hip_atomic_load(&flags[1], __ATOMIC_ACQUIRE, __HIP_MEMORY_SCOPE_AGENT) < ech)
                __builtin_amdgcn_s_sleep(32);
        }
        __syncthreads();
        __threadfence();
        csr_role(sm, binned, gcur0, off, deg, srt, n, bid - ech - pbh);
    }
}

// ---------------- D2: aggregate (R22, unchanged) ----------------
__global__ __launch_bounds__(256) void agg_kernel(const __half* __restrict__ xph,
                                                  const float* __restrict__ a_src,
                                                  const float* __restrict__ a_dst,
                                                  const int* __restrict__ off,
                                                  const int* __restrict__ deg,
                                                  const unsigned short* __restrict__ srt,
                                                  const float* __restrict__ bias,
                                                  float* __restrict__ out, int n) {
    int node_ = (blockIdx.x * blockDim.x + threadIdx.x) >> 6;
    if (node_ >= n) return;
    const int node = __builtin_amdgcn_readfirstlane(node_);   // wave-uniform -> SGPR
    const int lane = threadIdx.x & 63;
    const int g = lane >> 4;
    const unsigned l = (unsigned)(lane & 15);
    const unsigned h = l >> 2;
    const unsigned lo8 = l * 8u;

    const float ad = a_dst[((unsigned)node << 2) + h];

    float acc[8];
#pragma unroll
    for (int c = 0; c < 8; ++c) acc[c] = 0.f;
    float den = 0.f;

    if (g == 0) {   // self loop
        float t = a_src[((unsigned)node << 2) + h] + ad;
        float s = exp2f(fmaxf(t, NEG * t));
        half8 xv = *(const half8*)&xph[((unsigned)node << 7) + lo8];
#pragma unroll
        for (int c = 0; c < 8; ++c) acc[c] = s * (float)xv[c];
        den = s;
    }

    const int kb = off[node];
    const int ke = kb + deg[node];
    int k0 = kb;
    for (; k0 + 16 <= ke; k0 += 16) {
        const unsigned kg = (unsigned)(k0 + g * 4);
        const ushort4 s4 = *(const ushort4*)&srt[kg];
        unsigned sv[4] = {s4.x, s4.y, s4.z, s4.w};
        float asv[4];
        half8 hv[4];
#pragma unroll
        for (int j = 0; j < 4; ++j) asv[j] = a_src[(sv[j] << 2) + h];
#pragma unroll
        for (int j = 0; j < 4; ++j)
            hv[j] = *(const half8*)&xph[(sv[j] << 7) + lo8];
#pragma unroll
        for (int j = 0; j < 4; ++j) {
            float t = asv[j] + ad;
            const float s = exp2f(fmaxf(t, NEG * t));
#pragma unroll
            for (int c = 0; c < 8; ++c) acc[c] += s * (float)hv[j][c];
            den += s;
        }
    }
    if (k0 < ke) {   // predicated tail; srt reads stay in padded region
        const unsigned kg = (unsigned)(k0 + g * 4);
        const ushort4 s4 = *(const ushort4*)&srt[kg];
        const unsigned sv[4] = {s4.x, s4.y, s4.z, s4.w};
#pragma unroll
        for (int j = 0; j < 4; ++j) {
            if ((int)kg + j < ke) {
                float t = a_src[(sv[j] << 2) + h] + ad;
                const float s = exp2f(fmaxf(t, NEG * t));
                const half8 hv = *(const half8*)&xph[(sv[j] << 7) + lo8];
#pragma unroll
                for (int c = 0; c < 8; ++c) acc[c] += s * (float)hv[c];
                den += s;
            }
        }
    }

#pragma unroll
    for (int c = 0; c < 8; ++c) acc[c] += __shfl_xor(acc[c], 16, 64);
    den += __shfl_xor(den, 16, 64);
#pragma unroll
    for (int c = 0; c < 8; ++c) acc[c] += __shfl_xor(acc[c], 32, 64);
    den += __shfl_xor(den, 32, 64);

    if (lane < 16) {
        const float inv = 1.0f / den;
        const float4* b4 = (const float4*)&bias[lo8];
        float4 o0, o1;
        o0.x = acc[0] * inv + b4[0].x;
        o0.y = acc[1] * inv + b4[0].y;
        o0.z = acc[2] * inv + b4[0].z;
        o0.w = acc[3] * inv + b4[0].w;
        o1.x = acc[4] * inv + b4[1].x;
        o1.y = acc[5] * inv + b4[1].y;
        o1.z = acc[6] * inv + b4[1].z;
        o1.w = acc[7] * inv + b4[1].w;
        float4* d = (float4*)&out[((unsigned)node << 7) + lo8];
        d[0] = o0;
        d[1] = o1;
    }
}

// ---------------- launch ----------------
extern "C" void kernel_launch(void* const* d_in, const int* in_sizes, int n_in,
                              void* d_out, int out_size, void* d_ws, size_t ws_size,
                              hipStream_t stream) {
    if (n_in < 6 || !d_out || !d_ws) return;
    const float* x    = (const float*)d_in[0];
    const int*   ei   = (const int*)d_in[1];
    const float* W    = (const float*)d_in[2];
    const float* attS = (const float*)d_in[3];
    const float* attD = (const float*)d_in[4];
    const float* bias = (const float*)d_in[5];
    float* out = (float*)d_out;

    const int N = in_sizes[0] / DIN;
    const int E = in_sizes[1] / 2;
    if (N <= 0 || E <= 0) return;
    const int NBUCK = (N + 255) >> 8;
    const int ECH = (E + 4095) / 4096;
    const int PB  = (N + 63) / 64;
    const int PBH = (PB + 1) / 2;
    // guards: 16-bit src packing; 256-bucket scheme; wtrans needs >=64 bin blocks;
    // co-residency proof needs grid <= 1000 (4 blk/CU x 256 CU, margin)
    if (NBUCK > 256 || N > 65536 || ECH < 64 || ECH + PBH + NBUCK > 1000) return;

    char* ws = (char*)d_ws;
    size_t off_b = 0;
    auto carve = [&](size_t bytes) {
        size_t p = off_b;
        off_b = (off_b + bytes + 255) & ~(size_t)255;
        return (void*)(ws + p);
    };
    __half*         xph    = (__half*)carve((size_t)N * HC * 2);
    _Float16*       Wt     = (_Float16*)carve((size_t)HC * DIN * 2);
    float*          a_src  = (float*)carve((size_t)N * NH * 4);
    float*          a_dst  = (float*)carve((size_t)N * NH * 4);
    int*            gz     = (int*)carve(512 * 4);        // gcur0[256] + flags[2]
    unsigned*       binned = (unsigned*)carve((size_t)NBUCK * BCAP * 4);
    int*            offp   = (int*)carve((size_t)N * 4);
    int*            degp   = (int*)carve((size_t)N * 4);
    unsigned short* srt    = (unsigned short*)carve(((size_t)E + (size_t)NBUCK * 8192 + 64) * 2);
    (void)out_size;
    if (off_b > ws_size) return;

    int* gcur0 = gz;
    int* flags = gz + 256;

    hipMemsetAsync(gz, 0, 2048, stream);
    k_mega<<<ECH + PBH + NBUCK, 512, 0, stream>>>(ei, gcur0, flags, binned, x, W, Wt,
                                                  attS, attD, xph, a_src, a_dst,
                                                  offp, degp, srt, E, N, ECH, PBH, NBUCK);
    agg_kernel<<<(N * 64 + 255) / 256, 256, 0, stream>>>(xph, a_src, a_dst,
                                                         offp, degp, srt, bias, out, N);
}

// Round 14
// 406.407 us; speedup vs baseline: 1.4085x; 1.4085x over previous
//
#include <hip/hip_runtime.h>
#include <hip/hip_fp16.h>

// GATConv: N=50000, E=1600000, DIM_IN=256, HEADS=4, DIM_OUT=32 (HC=128)
// R24: R23's 468us failure root-caused: ACQUIRE atomic polls from 587 blocks
//   invalidated caches continuously. Fix: proj never polls (wtrans back in D0);
//   only 196 csr blocks wait, polling RELAXED (no cache ops) + ONE acquire fence
//   after exit. bin releases flags[0] after device fence. Co-residency: 978
//   blocks <= 1024 slots (36.9KB LDS -> 4/CU; lb(512,8)) -> no deadlock.
//   Pipeline: D0 zero+wtrans; D1 mega(bin||proj||csr); D2 agg (R22 unchanged).

#define DIN 256
#define HC 128
#define NH 4
#define NEG 0.2f
#define BCAP 12288
#define LOG2E 1.44269504f

typedef _Float16 half8 __attribute__((ext_vector_type(8)));
typedef _Float16 half2v __attribute__((ext_vector_type(2)));
typedef float f32x4 __attribute__((ext_vector_type(4)));

// ---------------- projection body (MFMA) + fused attention logits ----------------
// Per-sub-block sm layout (18432B): xs [64][40] halves @0; Wl [128][40] @5120;
//   ep [64][136] @0 (reused); attSL @17408, attDL @17920.
// tid = sub-block-local thread id (0..255).
// a_src/a_dst written PRE-SCALED by log2(e) for agg's exp2f.
__device__ __forceinline__ void proj_body(char* sm, int tid, const float* __restrict__ x,
                                          const _Float16* __restrict__ Wt,
                                          const float* __restrict__ attS,
                                          const float* __restrict__ attD,
                                          __half* __restrict__ xph,
                                          float* __restrict__ a_src,
                                          float* __restrict__ a_dst, int n, int node0) {
    _Float16* xs = (_Float16*)sm;
    _Float16* Wl = (_Float16*)(sm + 5120);
    _Float16* ep = (_Float16*)sm;
    float* attSL = (float*)(sm + 17408);
    float* attDL = (float*)(sm + 17920);

    const int wave = tid >> 6;
    const int lane = tid & 63;
    const int l15  = lane & 15;
    const int quad = lane >> 4;

    if (tid < 128) attSL[tid] = attS[tid];
    else           attDL[tid - 128] = attD[tid - 128];

    f32x4 acc[8];
#pragma unroll
    for (int ct = 0; ct < 8; ++ct) acc[ct] = (f32x4){0.f, 0.f, 0.f, 0.f};

    for (int kt = 0; kt < DIN; kt += 32) {
        __syncthreads();
#pragma unroll
        for (int r = 0; r < 4; ++r) {
            int idx = tid + r * 256;
            int row = idx >> 4;
            int kp  = idx & 15;
            int gn = node0 + row;
            float2 xv = make_float2(0.f, 0.f);
            if (gn < n) xv = *(const float2*)&x[(size_t)gn * DIN + kt + kp * 2];
            half2v p; p[0] = (_Float16)xv.x; p[1] = (_Float16)xv.y;
            *(half2v*)&xs[row * 40 + kp * 2] = p;
        }
#pragma unroll
        for (int r = 0; r < 2; ++r) {
            int id = tid + r * 256;
            int c = id >> 2;
            int q = id & 3;
            half8 wv = *(const half8*)&Wt[(size_t)c * 256 + kt + q * 8];
            *(half8*)&Wl[c * 40 + q * 8] = wv;
        }
        __syncthreads();
        half8 af = *(const half8*)&xs[(wave * 16 + l15) * 40 + quad * 8];
#pragma unroll
        for (int ct = 0; ct < 8; ++ct) {
            half8 bf = *(const half8*)&Wl[(ct * 16 + l15) * 40 + quad * 8];
            acc[ct] = __builtin_amdgcn_mfma_f32_16x16x32_f16(af, bf, acc[ct], 0, 0, 0);
        }
    }
    __syncthreads();
#pragma unroll
    for (int ct = 0; ct < 8; ++ct)
#pragma unroll
        for (int r = 0; r < 4; ++r) {
            int row = wave * 16 + quad * 4 + r;
            ep[row * 136 + ct * 16 + l15] = (_Float16)acc[ct][r];
        }
    __syncthreads();
    {
        int row = tid >> 2, ch = tid & 3;
        int node = node0 + row;
        if (node < n) {
            const uint4* s = (const uint4*)&ep[row * 136 + ch * 32];
            uint4* d = (uint4*)&xph[(size_t)node * HC + ch * 32];
            d[0] = s[0]; d[1] = s[1]; d[2] = s[2]; d[3] = s[3];
        }
    }
    {
        int nl = tid >> 2, h = tid & 3;
        int node = node0 + nl;
        if (node < n) {
            float ps = 0.f, pd = 0.f;
            const _Float16* er = &ep[nl * 136 + h * 32];
#pragma unroll
            for (int c = 0; c < 32; ++c) {
                float v = (float)er[c];
                ps += v * attSL[h * 32 + c];
                pd += v * attDL[h * 32 + c];
            }
            a_src[node * NH + h] = ps * LOG2E;
            a_dst[node * NH + h] = pd * LOG2E;
        }
    }
}

// ---------------- D0: zero gcur0+flags || wtrans ----------------
__global__ __launch_bounds__(256) void k_zero_wtrans(int* __restrict__ gz,
                                                     const float* __restrict__ W,
                                                     _Float16* __restrict__ Wt) {
    const int b = blockIdx.x;
    if (b < 2) {
        gz[b * 256 + threadIdx.x] = 0;
    } else {
        int i = (b - 2) * 256 + threadIdx.x;
        int k = i >> 7, c = i & 127;
        Wt[c * 256 + k] = (_Float16)W[i];
    }
}

// ---------------- bin role: one 4096-edge chunk, 512t, self-allocating buckets ----------------
__device__ __forceinline__ void bin_role(char* sm, const int* __restrict__ ei,
                                         int* __restrict__ gcur0,
                                         unsigned* __restrict__ binned,
                                         int e, int n, int chunk) {
    int* h     = (int*)sm;
    int* rbase = (int*)(sm + 1024);
    const int tid = threadIdx.x;
    if (tid < 256) h[tid] = 0;
    __syncthreads();
    const int base = chunk * 4096;
    unsigned pk[8];
    int bk[8];
#pragma unroll
    for (int j = 0; j < 8; ++j) {
        int i = base + j * 512 + tid;
        bk[j] = -1;
        if (i < e) {
            int src = ei[i];
            int dst = ei[e + i];
            if ((unsigned)dst < (unsigned)n && (unsigned)src < (unsigned)n) {
                bk[j] = dst >> 8;
                pk[j] = ((unsigned)(dst & 255) << 16) | (unsigned)src;
                atomicAdd(&h[bk[j]], 1);
            }
        }
    }
    __syncthreads();
    if (tid < 256) {
        if (h[tid]) rbase[tid] = atomicAdd(&gcur0[tid], h[tid]);
        h[tid] = 0;
    }
    __syncthreads();
#pragma unroll
    for (int j = 0; j < 8; ++j) {
        if (bk[j] >= 0) {
            int p = atomicAdd(&h[bk[j]], 1);
            int pib = rbase[bk[j]] + p;
            if (pib < BCAP) binned[(size_t)bk[j] * BCAP + pib] = pk[j];
        }
    }
}

// ---------------- csr role: one bucket counting sort, 512t two-pass ----------------
__device__ __forceinline__ void csr_role(char* sm, const unsigned* __restrict__ binned,
                                         const int* __restrict__ gcnt,
                                         int* __restrict__ off, int* __restrict__ deg,
                                         unsigned short* __restrict__ srt, int n, int b) {
    int* cnt = (int*)sm;
    int* buf = (int*)(sm + 1024);
    int* cur = (int*)(sm + 2048);
    const int tid = threadIdx.x;
    if (tid < 256) { buf[tid] = min(gcnt[tid], BCAP); cnt[tid] = 0; }
    __syncthreads();
    for (int s = 1; s < 256; s <<= 1) {
        int t = (tid < 256 && tid >= s) ? buf[tid - s] : 0;
        __syncthreads();
        if (tid < 256) buf[tid] += t;
        __syncthreads();
    }
    const int cb = min(gcnt[b], BCAP);
    const int excl = buf[b] - cb;                // exclusive scan of counts
    const int pgbase = ((excl + 31) & ~31) + b * 8192;
    const int kb = b * BCAP;
    const int ke = kb + cb;
    __syncthreads();                             // buf reads done before reuse
    for (int i = kb + tid; i < ke; i += 512)
        atomicAdd(&cnt[binned[i] >> 16], 1);
    __syncthreads();
    int v = 0;
    if (tid < 256) { v = cnt[tid]; buf[tid] = (v + 31) & ~31; }
    __syncthreads();
    for (int s = 1; s < 256; s <<= 1) {
        int t = (tid < 256 && tid >= s) ? buf[tid - s] : 0;
        __syncthreads();
        if (tid < 256) buf[tid] += t;
        __syncthreads();
    }
    if (tid < 256) {
        const int myoff = pgbase + buf[tid] - ((v + 31) & ~31);   // 32-aligned
        const int node = b * 256 + tid;
        if (node < n) { off[node] = myoff; deg[node] = v; }
        cur[tid] = myoff;
    }
    __syncthreads();
    for (int i = kb + tid; i < ke; i += 512) {
        unsigned pv = binned[i];
        int nl = pv >> 16;
        int pos = atomicAdd(&cur[nl], 1);
        srt[pos] = (unsigned short)(pv & 0xFFFFu);
    }
}

// ---------------- D1: fused bin || proj || csr (csr waits via RELAXED poll) ----------------
// 978 blocks all co-resident (4 blk/CU LDS x 256 CU = 1024 slots; lb(512,8))
// -> csr's spin cannot deadlock. proj has NO dependency (Wt from D0).
__global__ __launch_bounds__(512, 8) void k_mega(const int* __restrict__ ei,
                                                 int* __restrict__ gcur0,
                                                 int* __restrict__ flags,
                                                 unsigned* __restrict__ binned,
                                                 const float* __restrict__ x,
                                                 const _Float16* __restrict__ Wt,
                                                 const float* __restrict__ attS,
                                                 const float* __restrict__ attD,
                                                 __half* __restrict__ xph,
                                                 float* __restrict__ a_src,
                                                 float* __restrict__ a_dst,
                                                 int* __restrict__ off,
                                                 int* __restrict__ deg,
                                                 unsigned short* __restrict__ srt,
                                                 int e, int n, int ech, int pbh) {
    __shared__ __attribute__((aligned(16))) char sm[36864];
    const int bid = blockIdx.x;
    const int tid = threadIdx.x;

    if (bid < ech) {
        // ---- bin role; release flags[0] when done ----
        bin_role(sm, ei, gcur0, binned, e, n, bid);
        __threadfence();                            // binned/gcur0 visible device-wide
        __syncthreads();
        if (tid == 0)
            __hip_atomic_fetch_add(&flags[0], 1, __ATOMIC_RELEASE, __HIP_MEMORY_SCOPE_AGENT);
    } else if (bid < ech + pbh) {
        // ---- proj role: fully independent, no polling ----
        const int sub = tid >> 8;                   // 0 or 1
        const int t2  = tid & 255;
        const int tile = (bid - ech) * 2 + sub;
        proj_body(sm + sub * 18432, t2, x, Wt, attS, attD, xph, a_src, a_dst, n, tile * 64);
    } else {
        // ---- csr role: RELAXED poll (no cache ops) until all bins done ----
        if (tid == 0) {
            while (__hip_atomic_load(&flags[0], __ATOMIC_RELAXED, __HIP_MEMORY_SCOPE_AGENT) < ech)
                __builtin_amdgcn_s_sleep(64);
        }
        __syncthreads();
        __threadfence();                            // ONE acquire: invalidate once
        csr_role(sm, binned, gcur0, off, deg, srt, n, bid - ech - pbh);
    }
}

// ---------------- D2: aggregate (R22, unchanged) ----------------
__global__ __launch_bounds__(256) void agg_kernel(const __half* __restrict__ xph,
                                                  const float* __restrict__ a_src,
                                                  const float* __restrict__ a_dst,
                                                  const int* __restrict__ off,
                                                  const int* __restrict__ deg,
                                                  const unsigned short* __restrict__ srt,
                                                  const float* __restrict__ bias,
                                                  float* __restrict__ out, int n) {
    int node_ = (blockIdx.x * blockDim.x + threadIdx.x) >> 6;
    if (node_ >= n) return;
    const int node = __builtin_amdgcn_readfirstlane(node_);   // wave-uniform -> SGPR
    const int lane = threadIdx.x & 63;
    const int g = lane >> 4;
    const unsigned l = (unsigned)(lane & 15);
    const unsigned h = l >> 2;
    const unsigned lo8 = l * 8u;

    const float ad = a_dst[((unsigned)node << 2) + h];

    float acc[8];
#pragma unroll
    for (int c = 0; c < 8; ++c) acc[c] = 0.f;
    float den = 0.f;

    if (g == 0) {   // self loop
        float t = a_src[((unsigned)node << 2) + h] + ad;
        float s = exp2f(fmaxf(t, NEG * t));
        half8 xv = *(const half8*)&xph[((unsigned)node << 7) + lo8];
#pragma unroll
        for (int c = 0; c < 8; ++c) acc[c] = s * (float)xv[c];
        den = s;
    }

    const int kb = off[node];
    const int ke = kb + deg[node];
    int k0 = kb;
    for (; k0 + 16 <= ke; k0 += 16) {
        const unsigned kg = (unsigned)(k0 + g * 4);
        const ushort4 s4 = *(const ushort4*)&srt[kg];
        unsigned sv[4] = {s4.x, s4.y, s4.z, s4.w};
        float asv[4];
        half8 hv[4];
#pragma unroll
        for (int j = 0; j < 4; ++j) asv[j] = a_src[(sv[j] << 2) + h];
#pragma unroll
        for (int j = 0; j < 4; ++j)
            hv[j] = *(const half8*)&xph[(sv[j] << 7) + lo8];
#pragma unroll
        for (int j = 0; j < 4; ++j) {
            float t = asv[j] + ad;
            const float s = exp2f(fmaxf(t, NEG * t));
#pragma unroll
            for (int c = 0; c < 8; ++c) acc[c] += s * (float)hv[j][c];
            den += s;
        }
    }
    if (k0 < ke) {   // predicated tail; srt reads stay in padded region
        const unsigned kg = (unsigned)(k0 + g * 4);
        const ushort4 s4 = *(const ushort4*)&srt[kg];
        const unsigned sv[4] = {s4.x, s4.y, s4.z, s4.w};
#pragma unroll
        for (int j = 0; j < 4; ++j) {
            if ((int)kg + j < ke) {
                float t = a_src[(sv[j] << 2) + h] + ad;
                const float s = exp2f(fmaxf(t, NEG * t));
                const half8 hv = *(const half8*)&xph[(sv[j] << 7) + lo8];
#pragma unroll
                for (int c = 0; c < 8; ++c) acc[c] += s * (float)hv[c];
                den += s;
            }
        }
    }

#pragma unroll
    for (int c = 0; c < 8; ++c) acc[c] += __shfl_xor(acc[c], 16, 64);
    den += __shfl_xor(den, 16, 64);
#pragma unroll
    for (int c = 0; c < 8; ++c) acc[c] += __shfl_xor(acc[c], 32, 64);
    den += __shfl_xor(den, 32, 64);

    if (lane < 16) {
        const float inv = 1.0f / den;
        const float4* b4 = (const float4*)&bias[lo8];
        float4 o0, o1;
        o0.x = acc[0] * inv + b4[0].x;
        o0.y = acc[1] * inv + b4[0].y;
        o0.z = acc[2] * inv + b4[0].z;
        o0.w = acc[3] * inv + b4[0].w;
        o1.x = acc[4] * inv + b4[1].x;
        o1.y = acc[5] * inv + b4[1].y;
        o1.z = acc[6] * inv + b4[1].z;
        o1.w = acc[7] * inv + b4[1].w;
        float4* d = (float4*)&out[((unsigned)node << 7) + lo8];
        d[0] = o0;
        d[1] = o1;
    }
}

// ---------------- launch ----------------
extern "C" void kernel_launch(void* const* d_in, const int* in_sizes, int n_in,
                              void* d_out, int out_size, void* d_ws, size_t ws_size,
                              hipStream_t stream) {
    if (n_in < 6 || !d_out || !d_ws) return;
    const float* x    = (const float*)d_in[0];
    const int*   ei   = (const int*)d_in[1];
    const float* W    = (const float*)d_in[2];
    const float* attS = (const float*)d_in[3];
    const float* attD = (const float*)d_in[4];
    const float* bias = (const float*)d_in[5];
    float* out = (float*)d_out;

    const int N = in_sizes[0] / DIN;
    const int E = in_sizes[1] / 2;
    if (N <= 0 || E <= 0) return;
    const int NBUCK = (N + 255) >> 8;
    const int ECH = (E + 4095) / 4096;
    const int PB  = (N + 63) / 64;
    const int PBH = (PB + 1) / 2;
    // guards: 16-bit src packing; 256-bucket scheme; co-residency (deadlock-free
    // spin) needs grid <= 1000 (4 blk/CU x 256 CU, margin)
    if (NBUCK > 256 || N > 65536 || ECH + PBH + NBUCK > 1000) return;

    char* ws = (char*)d_ws;
    size_t off_b = 0;
    auto carve = [&](size_t bytes) {
        size_t p = off_b;
        off_b = (off_b + bytes + 255) & ~(size_t)255;
        return (void*)(ws + p);
    };
    __half*         xph    = (__half*)carve((size_t)N * HC * 2);
    _Float16*       Wt     = (_Float16*)carve((size_t)HC * DIN * 2);
    float*          a_src  = (float*)carve((size_t)N * NH * 4);
    float*          a_dst  = (float*)carve((size_t)N * NH * 4);
    int*            gz     = (int*)carve(512 * 4);        // gcur0[256] + flags
    unsigned*       binned = (unsigned*)carve((size_t)NBUCK * BCAP * 4);
    int*            offp   = (int*)carve((size_t)N * 4);
    int*            degp   = (int*)carve((size_t)N * 4);
    unsigned short* srt    = (unsigned short*)carve(((size_t)E + (size_t)NBUCK * 8192 + 64) * 2);
    (void)out_size;
    if (off_b > ws_size) return;

    int* gcur0 = gz;
    int* flags = gz + 256;

    k_zero_wtrans<<<2 + 128, 256, 0, stream>>>(gz, W, Wt);
    k_mega<<<ECH + PBH + NBUCK, 512, 0, stream>>>(ei, gcur0, flags, binned, x, Wt,
                                                  attS, attD, xph, a_src, a_dst,
                                                  offp, degp, srt, E, N, ECH, PBH);
    agg_kernel<<<(N * 64 + 255) / 256, 256, 0, stream>>>(xph, a_src, a_dst,
                                                         offp, degp, srt, bias, out, N);
}